// Round 2
// baseline (250.524 us; speedup 1.0000x reference)
//
#include <hip/hip_runtime.h>

typedef __attribute__((ext_vector_type(8))) short short8;
typedef __attribute__((ext_vector_type(4))) float floatx4;

// ---- problem constants ----
#define BS   32768
#define NIN  512
#define NE   8
#define NH   256
// We flat: e*131072 + k*256 + h ; WeT flat: e*131072 + h*512 + k

__device__ __forceinline__ unsigned short f2bf(float f) {
  unsigned int u = __float_as_uint(f);
  u += 0x7fffu + ((u >> 16) & 1u);   // round-to-nearest-even
  return (unsigned short)(u >> 16);
}

// Transpose We [8][512][256] f32 -> WeT [8][256][512] bf16 (k-contiguous rows)
__global__ void prep_weT(const float* __restrict__ We, unsigned short* __restrict__ WeT) {
  int e  = blockIdx.x >> 6;   // 8
  int kc = blockIdx.x & 63;   // 64 chunks of 8 k
  int h  = threadIdx.x;       // 256
  short8 pk;
#pragma unroll
  for (int j = 0; j < 8; ++j)
    pk[j] = (short)f2bf(We[e * 131072 + (kc * 8 + j) * 256 + h]);
  *reinterpret_cast<short8*>(&WeT[e * 131072 + h * 512 + kc * 8]) = pk;
}

// Wg [2][512][8] f32 -> WgT [16][512] bf16, row = t*8+e
__global__ void prep_wgT(const float* __restrict__ Wg, unsigned short* __restrict__ WgT) {
  int row = blockIdx.x;             // 16
  int t = row >> 3, e = row & 7;
  int lane = threadIdx.x;           // 64
  short8 pk;
#pragma unroll
  for (int j = 0; j < 8; ++j)
    pk[j] = (short)f2bf(Wg[t * 4096 + (lane * 8 + j) * 8 + e]);
  *reinterpret_cast<short8*>(&WgT[row * 512 + lane * 8]) = pk;
}

// 512 threads = 8 waves, wave grid 2(m: wm=wave>>2) x 4(n: wn=wave&3).
// Each wave: 2 m-frags (32 rows) x 4 n-frags (64 cols). 2 blocks/CU -> 4 waves/SIMD.
__global__ __launch_bounds__(512, 4) void mmoe_main(
    const float* __restrict__ xv,            // [32768,512]
    const unsigned short* __restrict__ WeT,  // [8][256][512] bf16
    const unsigned short* __restrict__ WgT,  // [16][512] bf16
    const float* __restrict__ be,            // [8][256]
    const float* __restrict__ bg,            // [2][8]
    const float* __restrict__ Wt,            // [2][256]
    const float* __restrict__ bt,            // [2]
    float* __restrict__ out)                 // [2][32768] concat
{
  __shared__ __align__(16) unsigned char A_lds[64 * 1024]; // 64 rows x 512 bf16, swizzled
  __shared__ float gates_lds[64][17];                       // +1 pad avoids bank clash
  __shared__ float red_lds[8][32][2];

  const int tid   = threadIdx.x;
  const int wave  = tid >> 6;
  const int lane  = tid & 63;
  const int row16 = lane & 15;   // fragment row / output col id
  const int kgrp  = lane >> 4;   // which 8-wide k slice of the frag
  const int wm    = wave >> 2;   // 0..1 : which 32-row half
  const int wn    = wave & 3;    // 0..3 : which 64-col group
  const int b0    = blockIdx.x * 64;

  // ---- stage A tile (64 x 512) fp32 -> bf16, XOR-swizzled (G4: byte ^= (row&7)<<4) ----
#pragma unroll
  for (int i = 0; i < 8; ++i) {
    int idx = i * 512 + tid;
    int r = idx >> 6, c = idx & 63;           // 16B chunk c within row r
    const float4* src = reinterpret_cast<const float4*>(xv + (size_t)(b0 + r) * 512 + c * 8);
    float4 v0 = src[0];
    float4 v1 = src[1];
    short8 pk;
    pk[0] = (short)f2bf(v0.x); pk[1] = (short)f2bf(v0.y);
    pk[2] = (short)f2bf(v0.z); pk[3] = (short)f2bf(v0.w);
    pk[4] = (short)f2bf(v1.x); pk[5] = (short)f2bf(v1.y);
    pk[6] = (short)f2bf(v1.z); pk[7] = (short)f2bf(v1.w);
    unsigned addr = ((unsigned)(r << 10) + (unsigned)(c << 4)) ^ (unsigned)((r & 7) << 4);
    *reinterpret_cast<short8*>(&A_lds[addr]) = pk;
  }
  __syncthreads();

  // disjoint bit fields: row16<<10 | kgrp<<4 ; frag<<14, ks<<6 added later; XOR last
  const unsigned a_lane = ((unsigned)row16 << 10) + ((unsigned)kgrp << 4);
  const unsigned a_swz  = (unsigned)((row16 & 7) << 4);

  // per-lane tower weights for this wave's 4 n-frags (independent of gates sync)
  float wtv[2][4];
#pragma unroll
  for (int t = 0; t < 2; ++t)
#pragma unroll
    for (int n = 0; n < 4; ++n)
      wtv[t][n] = Wt[t * 256 + wn * 64 + n * 16 + row16];

  // ---- gates: waves 0..3 compute m-frag `wave`; softmax over experts ----
  if (wave < 4) {
    floatx4 gacc = {0.f, 0.f, 0.f, 0.f};
    const unsigned abase = a_lane + ((unsigned)wave << 14);
    const unsigned short* wg_lane = WgT + row16 * 512 + kgrp * 8;
#pragma unroll
    for (int ks = 0; ks < 16; ++ks) {
      short8 af = *reinterpret_cast<const short8*>(&A_lds[(abase + (unsigned)(ks << 6)) ^ a_swz]);
      short8 bf = *reinterpret_cast<const short8*>(wg_lane + ks * 32);
      gacc = __builtin_amdgcn_mfma_f32_16x16x32_bf16(af, bf, gacc, 0, 0, 0);
    }
    float bgv = bg[row16];   // col = t*8+e
#pragma unroll
    for (int j = 0; j < 4; ++j) {
      float v = gacc[j] + bgv;
      float mx = v;
      mx = fmaxf(mx, __shfl_xor(mx, 1));
      mx = fmaxf(mx, __shfl_xor(mx, 2));
      mx = fmaxf(mx, __shfl_xor(mx, 4));
      float p = __expf(v - mx);
      float s = p;
      s += __shfl_xor(s, 1);
      s += __shfl_xor(s, 2);
      s += __shfl_xor(s, 4);
      gates_lds[wave * 16 + kgrp * 4 + j][row16] = p / s;
    }
  }
  __syncthreads();

  // ---- expert loop: GEMM tile -> relu -> Wt-dot -> gate-weighted accumulate ----
  float outacc[2][4][2];
#pragma unroll
  for (int m = 0; m < 2; ++m)
#pragma unroll
    for (int j = 0; j < 4; ++j) { outacc[m][j][0] = 0.f; outacc[m][j][1] = 0.f; }

  const unsigned fm0 = (unsigned)(wm * 2);   // first of this wave's 2 m-frags

  for (int e = 0; e < 8; ++e) {
    floatx4 acc[2][4];
#pragma unroll
    for (int m = 0; m < 2; ++m)
#pragma unroll
      for (int n = 0; n < 4; ++n) acc[m][n] = (floatx4){0.f, 0.f, 0.f, 0.f};

    const unsigned short* wB_lane = WeT + e * 131072 + (wn * 64 + row16) * 512 + kgrp * 8;

#pragma unroll 2
    for (int ks = 0; ks < 16; ++ks) {
      short8 af[2], bfv[4];
#pragma unroll
      for (int m = 0; m < 2; ++m)
        af[m] = *reinterpret_cast<const short8*>(
            &A_lds[(a_lane + ((fm0 + m) << 14) + (unsigned)(ks << 6)) ^ a_swz]);
#pragma unroll
      for (int n = 0; n < 4; ++n)
        bfv[n] = *reinterpret_cast<const short8*>(wB_lane + n * 8192 + ks * 32);
#pragma unroll
      for (int m = 0; m < 2; ++m)
#pragma unroll
        for (int n = 0; n < 4; ++n)
          acc[m][n] = __builtin_amdgcn_mfma_f32_16x16x32_bf16(af[m], bfv[n], acc[m][n], 0, 0, 0);
    }

    float bev[4];
#pragma unroll
    for (int n = 0; n < 4; ++n)
      bev[n] = be[e * 256 + wn * 64 + n * 16 + row16];

#pragma unroll
    for (int m = 0; m < 2; ++m) {
#pragma unroll
      for (int j = 0; j < 4; ++j) {
        int row = (fm0 + m) * 16 + kgrp * 4 + j;   // global row 0..63
        float p0 = 0.f, p1 = 0.f;
#pragma unroll
        for (int n = 0; n < 4; ++n) {
          float r = fmaxf(acc[m][n][j] + bev[n], 0.f);
          p0 = fmaf(r, wtv[0][n], p0);
          p1 = fmaf(r, wtv[1][n], p1);
        }
        outacc[m][j][0] = fmaf(gates_lds[row][e],     p0, outacc[m][j][0]);
        outacc[m][j][1] = fmaf(gates_lds[row][8 + e], p1, outacc[m][j][1]);
      }
    }
  }

  // ---- butterfly-reduce over the 16 col-lanes, then cross-wave (over wn) via LDS ----
#pragma unroll
  for (int m = 0; m < 2; ++m)
#pragma unroll
    for (int j = 0; j < 4; ++j)
#pragma unroll
      for (int t = 0; t < 2; ++t) {
        float v = outacc[m][j][t];
        v += __shfl_xor(v, 1);
        v += __shfl_xor(v, 2);
        v += __shfl_xor(v, 4);
        v += __shfl_xor(v, 8);
        outacc[m][j][t] = v;
      }
  if (row16 == 0) {
#pragma unroll
    for (int m = 0; m < 2; ++m)
#pragma unroll
      for (int j = 0; j < 4; ++j) {
        int lr = m * 16 + kgrp * 4 + j;            // local row within wave's 32 rows
        red_lds[wave][lr][0] = outacc[m][j][0];
        red_lds[wave][lr][1] = outacc[m][j][1];
      }
  }
  __syncthreads();

  if (tid < 128) {
    int row = tid >> 1, t = tid & 1;               // row 0..63
    int wmr = row >> 5, lr = row & 31;
    float s = red_lds[wmr * 4 + 0][lr][t] + red_lds[wmr * 4 + 1][lr][t]
            + red_lds[wmr * 4 + 2][lr][t] + red_lds[wmr * 4 + 3][lr][t];
    s += bt[t];
    s = fmaxf(s, 0.f);
    out[t * BS + b0 + row] = 1.f / (1.f + __expf(-s));
  }
}

extern "C" void kernel_launch(void* const* d_in, const int* in_sizes, int n_in,
                              void* d_out, int out_size, void* d_ws, size_t ws_size,
                              hipStream_t stream) {
  const float* xv = (const float*)d_in[0];
  const float* We = (const float*)d_in[1];
  const float* be = (const float*)d_in[2];
  const float* Wg = (const float*)d_in[3];
  const float* bg = (const float*)d_in[4];
  const float* Wt = (const float*)d_in[5];
  const float* bt = (const float*)d_in[6];
  float* out = (float*)d_out;

  unsigned short* WeT = (unsigned short*)d_ws;            // 8*256*512*2B = 2 MiB
  unsigned short* WgT = WeT + 8 * 256 * 512;              // 16*512*2B   = 16 KiB

  prep_weT<<<512, 256, 0, stream>>>(We, WeT);
  prep_wgT<<<16, 64, 0, stream>>>(Wg, WgT);
  mmoe_main<<<512, 512, 0, stream>>>(xv, WeT, WgT, be, bg, Wt, bt, out);
}

// Round 3
// 108.285 us; speedup vs baseline: 2.3136x; 2.3136x over previous
//
#include <hip/hip_runtime.h>

typedef __attribute__((ext_vector_type(8))) short short8;
typedef __attribute__((ext_vector_type(4))) float floatx4;

#define BS   32768
#define NIN  512
#define NE   8
#define NH   256

__device__ __forceinline__ unsigned short f2bf(float f) {
  unsigned int u = __float_as_uint(f);
  u += 0x7fffu + ((u >> 16) & 1u);   // round-to-nearest-even
  return (unsigned short)(u >> 16);
}

// Transpose We [8][512][256] f32 -> WeT [8][256][512] bf16 (k-contiguous rows)
__global__ void prep_weT(const float* __restrict__ We, unsigned short* __restrict__ WeT) {
  int e  = blockIdx.x >> 6;
  int kc = blockIdx.x & 63;
  int h  = threadIdx.x;
  short8 pk;
#pragma unroll
  for (int j = 0; j < 8; ++j)
    pk[j] = (short)f2bf(We[e * 131072 + (kc * 8 + j) * 256 + h]);
  *reinterpret_cast<short8*>(&WeT[e * 131072 + h * 512 + kc * 8]) = pk;
}

// Wg [2][512][8] f32 -> WgT [16][512] bf16, row = t*8+e
__global__ void prep_wgT(const float* __restrict__ Wg, unsigned short* __restrict__ WgT) {
  int row = blockIdx.x;
  int t = row >> 3, e = row & 7;
  int lane = threadIdx.x;
  short8 pk;
#pragma unroll
  for (int j = 0; j < 8; ++j)
    pk[j] = (short)f2bf(Wg[t * 4096 + (lane * 8 + j) * 8 + e]);
  *reinterpret_cast<short8*>(&WgT[row * 512 + lane * 8]) = pk;
}

#define GLOAD16(SRC, DST) \
  __builtin_amdgcn_global_load_lds( \
      (const __attribute__((address_space(1))) unsigned int*)(SRC), \
      (__attribute__((address_space(3))) unsigned int*)(DST), 16, 0, 0)

// 512 thr = 8 waves, grid 2m x 4n. Wave tile 32m x 64n (2 m-frags x 4 n-frags, 16x16x32).
// A (full K) lives in registers (128 VGPR/lane). B double-buffered in LDS via
// global_load_lds with pre-swizzled source; one expert x BK=128 per phase.
__global__ __launch_bounds__(512, 2) void mmoe_main(
    const float* __restrict__ xv,            // [32768,512]
    const unsigned short* __restrict__ WeT,  // [8][256][512] bf16
    const unsigned short* __restrict__ WgT,  // [16][512] bf16
    const float* __restrict__ be,            // [8][256]
    const float* __restrict__ bg,            // [2][8]
    const float* __restrict__ Wt,            // [2][256]
    const float* __restrict__ bt,            // [2]
    float* __restrict__ out)                 // [2][32768]
{
  __shared__ __attribute__((aligned(16))) unsigned char smem[131072]; // buf0 | buf1 (buf1 = transient A)
  __shared__ float gates_lds[64][17];
  __shared__ float red_lds[8][32][2];

  const int tid   = threadIdx.x;
  const int wave  = tid >> 6;
  const int lane  = tid & 63;
  const int row16 = lane & 15;
  const int kgrp  = lane >> 4;
  const int wm    = wave >> 2;   // 0..1
  const int wn    = wave & 3;    // 0..3
  const int b0    = blockIdx.x * 64;

  unsigned char* buf0 = smem;
  unsigned char* bufA = smem + 65536;  // == buf1

  // ---- reg-stage A tile (64 x 512) fp32->bf16 into bufA, swizzled (byte ^= (r&7)<<4) ----
#pragma unroll
  for (int i = 0; i < 8; ++i) {
    int idx = i * 512 + tid;
    int r = idx >> 6, c = idx & 63;
    const float4* src = reinterpret_cast<const float4*>(xv + (size_t)(b0 + r) * 512 + c * 8);
    float4 v0 = src[0];
    float4 v1 = src[1];
    short8 pk;
    pk[0] = (short)f2bf(v0.x); pk[1] = (short)f2bf(v0.y);
    pk[2] = (short)f2bf(v0.z); pk[3] = (short)f2bf(v0.w);
    pk[4] = (short)f2bf(v1.x); pk[5] = (short)f2bf(v1.y);
    pk[6] = (short)f2bf(v1.z); pk[7] = (short)f2bf(v1.w);
    unsigned addr = ((unsigned)(r << 10) + (unsigned)(c << 4)) ^ (unsigned)((r & 7) << 4);
    *reinterpret_cast<short8*>(&bufA[addr]) = pk;
  }

  // ---- issue B stage for phase 0 (e=0, kc=0) -> buf0 (pre-swizzled source) ----
  // LDS logical: [256 h rows][256B of k], stored byte = row*256 + (kbyte ^ ((row&15)<<4))
  {
#pragma unroll
    for (int i = 0; i < 8; ++i) {
      unsigned x = (unsigned)(i * 8192 + tid * 16);
      unsigned r = x >> 8;
      unsigned y = (x & 255u) ^ ((r & 15u) << 4);
      const unsigned short* src = WeT + ((0 * 256 + r) * 512 + 0 * 128 + (y >> 1));
      GLOAD16(src, buf0 + (i * 8 + wave) * 1024);
    }
  }
  __syncthreads();   // A writes + phase-0 B loads drained

  // ---- gates: waves 0..3 compute m-frag `wave`; softmax over experts ----
  if (wave < 4) {
    floatx4 gacc = {0.f, 0.f, 0.f, 0.f};
    const unsigned abase = ((unsigned)row16 << 10) + ((unsigned)kgrp << 4) + ((unsigned)wave << 14);
    const unsigned a_swz = (unsigned)((row16 & 7) << 4);
    const unsigned short* wg_lane = WgT + row16 * 512 + kgrp * 8;
#pragma unroll
    for (int ks = 0; ks < 16; ++ks) {
      short8 af = *reinterpret_cast<const short8*>(&bufA[(abase + (unsigned)(ks << 6)) ^ a_swz]);
      short8 bf = *reinterpret_cast<const short8*>(wg_lane + ks * 32);
      gacc = __builtin_amdgcn_mfma_f32_16x16x32_bf16(af, bf, gacc, 0, 0, 0);
    }
    float bgv = bg[row16];
#pragma unroll
    for (int j = 0; j < 4; ++j) {
      float v = gacc[j] + bgv;
      float mx = v;
      mx = fmaxf(mx, __shfl_xor(mx, 1));
      mx = fmaxf(mx, __shfl_xor(mx, 2));
      mx = fmaxf(mx, __shfl_xor(mx, 4));
      float p = __expf(v - mx);
      float s = p;
      s += __shfl_xor(s, 1);
      s += __shfl_xor(s, 2);
      s += __shfl_xor(s, 4);
      gates_lds[wave * 16 + kgrp * 4 + j][row16] = p / s;
    }
  }

  // ---- A-reg fill: 2 m-frags x 16 k-chunks per lane (128 VGPRs) ----
  short8 a_reg[2][16];
  {
    const unsigned a_swz = (unsigned)((row16 & 7) << 4);
#pragma unroll
    for (int m2 = 0; m2 < 2; ++m2) {
      const unsigned rbase = (unsigned)((wm * 2 + m2) * 16 + row16) << 10;
#pragma unroll
      for (int c = 0; c < 16; ++c)
        a_reg[m2][c] = *reinterpret_cast<const short8*>(
            &bufA[rbase + (((unsigned)(c << 6) + ((unsigned)kgrp << 4)) ^ a_swz)]);
    }
  }

  // per-lane tower weights for this wave's 4 n-frags
  float wtv[2][4];
#pragma unroll
  for (int t = 0; t < 2; ++t)
#pragma unroll
    for (int n = 0; n < 4; ++n)
      wtv[t][n] = Wt[t * 256 + wn * 64 + n * 16 + row16];

  __syncthreads();   // A-reg fill + gates done; bufA free for B double-buffering

  // ---- main loop: 8 experts x 4 k-chunks; B from LDS, A from regs ----
  float outacc[2][4][2];
#pragma unroll
  for (int m = 0; m < 2; ++m)
#pragma unroll
    for (int j = 0; j < 4; ++j) { outacc[m][j][0] = 0.f; outacc[m][j][1] = 0.f; }

  const unsigned b_swz = (unsigned)(row16 << 4);
  const unsigned b_col = (unsigned)(wn * 64 + row16);   // + n*16

  for (int e = 0; e < 8; ++e) {
    floatx4 acc[2][4];
#pragma unroll
    for (int m = 0; m < 2; ++m)
#pragma unroll
      for (int n = 0; n < 4; ++n) acc[m][n] = (floatx4){0.f, 0.f, 0.f, 0.f};

#pragma unroll
    for (int kc = 0; kc < 4; ++kc) {
      // stage next phase into the other buffer
      unsigned char* sbuf = (kc & 1) ? buf0 : bufA;
      const int ne  = (kc < 3) ? e : e + 1;
      const int nkc = (kc + 1) & 3;
      if (kc < 3 || e < 7) {
#pragma unroll
        for (int i = 0; i < 8; ++i) {
          unsigned x = (unsigned)(i * 8192 + tid * 16);
          unsigned r = x >> 8;
          unsigned y = (x & 255u) ^ ((r & 15u) << 4);
          const unsigned short* src = WeT + ((ne * 256 + (int)r) * 512 + nkc * 128 + (int)(y >> 1));
          GLOAD16(src, sbuf + (i * 8 + wave) * 1024);
        }
      }

      const unsigned char* cb = (kc & 1) ? bufA : buf0;
#pragma unroll
      for (int ks = 0; ks < 4; ++ks) {
        short8 bfv[4];
#pragma unroll
        for (int n = 0; n < 4; ++n) {
          unsigned col = b_col + (unsigned)(n * 16);
          unsigned kb  = ((unsigned)(ks * 64 + kgrp * 16)) ^ b_swz;
          bfv[n] = *reinterpret_cast<const short8*>(&cb[col * 256 + kb]);
        }
#pragma unroll
        for (int m2 = 0; m2 < 2; ++m2)
#pragma unroll
          for (int n = 0; n < 4; ++n)
            acc[m2][n] = __builtin_amdgcn_mfma_f32_16x16x32_bf16(
                a_reg[m2][kc * 4 + ks], bfv[n], acc[m2][n], 0, 0, 0);
      }
      __syncthreads();   // drains vmcnt (next-phase stage) + lgkm; phase barrier
    }

    // ---- epilogue for expert e: bias+relu -> Wt-dot -> gate-weighted accumulate ----
    float bev[4];
#pragma unroll
    for (int n = 0; n < 4; ++n)
      bev[n] = be[e * 256 + wn * 64 + n * 16 + row16];

#pragma unroll
    for (int m2 = 0; m2 < 2; ++m2) {
#pragma unroll
      for (int j = 0; j < 4; ++j) {
        int row = (wm * 2 + m2) * 16 + kgrp * 4 + j;
        float p0 = 0.f, p1 = 0.f;
#pragma unroll
        for (int n = 0; n < 4; ++n) {
          float r = fmaxf(acc[m2][n][j] + bev[n], 0.f);
          p0 = fmaf(r, wtv[0][n], p0);
          p1 = fmaf(r, wtv[1][n], p1);
        }
        outacc[m2][j][0] = fmaf(gates_lds[row][e],     p0, outacc[m2][j][0]);
        outacc[m2][j][1] = fmaf(gates_lds[row][8 + e], p1, outacc[m2][j][1]);
      }
    }
  }

  // ---- reduce over 16 col-lanes, then across the 4 n-waves via LDS ----
#pragma unroll
  for (int m = 0; m < 2; ++m)
#pragma unroll
    for (int j = 0; j < 4; ++j)
#pragma unroll
      for (int t = 0; t < 2; ++t) {
        float v = outacc[m][j][t];
        v += __shfl_xor(v, 1);
        v += __shfl_xor(v, 2);
        v += __shfl_xor(v, 4);
        v += __shfl_xor(v, 8);
        outacc[m][j][t] = v;
      }
  if (row16 == 0) {
#pragma unroll
    for (int m = 0; m < 2; ++m)
#pragma unroll
      for (int j = 0; j < 4; ++j) {
        int lr = m * 16 + kgrp * 4 + j;
        red_lds[wave][lr][0] = outacc[m][j][0];
        red_lds[wave][lr][1] = outacc[m][j][1];
      }
  }
  __syncthreads();

  if (tid < 128) {
    int row = tid >> 1, t = tid & 1;
    int wmr = row >> 5, lr = row & 31;
    float s = red_lds[wmr * 4 + 0][lr][t] + red_lds[wmr * 4 + 1][lr][t]
            + red_lds[wmr * 4 + 2][lr][t] + red_lds[wmr * 4 + 3][lr][t];
    s += bt[t];
    s = fmaxf(s, 0.f);
    out[t * BS + b0 + row] = 1.f / (1.f + __expf(-s));
  }
}

extern "C" void kernel_launch(void* const* d_in, const int* in_sizes, int n_in,
                              void* d_out, int out_size, void* d_ws, size_t ws_size,
                              hipStream_t stream) {
  const float* xv = (const float*)d_in[0];
  const float* We = (const float*)d_in[1];
  const float* be = (const float*)d_in[2];
  const float* Wg = (const float*)d_in[3];
  const float* bg = (const float*)d_in[4];
  const float* Wt = (const float*)d_in[5];
  const float* bt = (const float*)d_in[6];
  float* out = (float*)d_out;

  unsigned short* WeT = (unsigned short*)d_ws;            // 2 MiB
  unsigned short* WgT = WeT + 8 * 256 * 512;              // 16 KiB

  prep_weT<<<512, 256, 0, stream>>>(We, WeT);
  prep_wgT<<<16, 64, 0, stream>>>(Wg, WgT);
  mmoe_main<<<512, 512, 0, stream>>>(xv, WeT, WgT, be, bg, Wt, bt, out);
}